// Round 2
// baseline (34.121 us; speedup 1.0000x reference)
//
#include <hip/hip_runtime.h>

// Problem constants (from reference): E=8, B=4, S=4096, H=1024, K=2
static constexpr int kB = 4;
static constexpr int kS = 4096;
static constexpr int kH = 1024;
static constexpr int kK = 2;
static constexpr int kTokens = kB * kS;                  // 16384
static constexpr size_t kBSH = (size_t)kB * kS * kH;     // 16,777,216

// Two tokens per block; 256 threads x float4 = one H-row (1024 f32) per token.
// Per-token dedup when both expert indices coincide (P=1/8 with E=8).
__global__ __launch_bounds__(256) void FusedExpertMixer_kernel(
    const float* __restrict__ expert_stack,   // [E,B,S,H]
    const float* __restrict__ expert_weights, // [B,S,K]
    const int*   __restrict__ expert_indices, // [B,S,K]
    float* __restrict__ out)                  // [B,S,H]
{
    const int ta = blockIdx.x * 2;            // first token of the pair
    const int tb = ta + 1;
    const int h  = threadIdx.x;               // float4 slot 0..255

    // Wave-uniform scalar loads for both tokens.
    const int   e0a = expert_indices[ta * kK + 0];
    const int   e1a = expert_indices[ta * kK + 1];
    const float w0a = expert_weights[ta * kK + 0];
    const float w1a = expert_weights[ta * kK + 1];

    const int   e0b = expert_indices[tb * kK + 0];
    const int   e1b = expert_indices[tb * kK + 1];
    const float w0b = expert_weights[tb * kK + 0];
    const float w1b = expert_weights[tb * kK + 1];

    const float4* __restrict__ pa0 =
        (const float4*)(expert_stack + (size_t)e0a * kBSH + (size_t)ta * kH);
    const float4* __restrict__ pa1 =
        (const float4*)(expert_stack + (size_t)e1a * kBSH + (size_t)ta * kH);
    const float4* __restrict__ pb0 =
        (const float4*)(expert_stack + (size_t)e0b * kBSH + (size_t)tb * kH);
    const float4* __restrict__ pb1 =
        (const float4*)(expert_stack + (size_t)e1b * kBSH + (size_t)tb * kH);

    float4 ra, rb;

    if (e1a == e0a) {
        // Duplicate expert: single load, combined weight.
        const float w = w0a + w1a;
        const float4 v = pa0[h];
        ra.x = w * v.x; ra.y = w * v.y; ra.z = w * v.z; ra.w = w * v.w;
    } else {
        const float4 v0 = pa0[h];
        const float4 v1 = pa1[h];
        ra.x = w0a * v0.x + w1a * v1.x;
        ra.y = w0a * v0.y + w1a * v1.y;
        ra.z = w0a * v0.z + w1a * v1.z;
        ra.w = w0a * v0.w + w1a * v1.w;
    }

    if (e1b == e0b) {
        const float w = w0b + w1b;
        const float4 v = pb0[h];
        rb.x = w * v.x; rb.y = w * v.y; rb.z = w * v.z; rb.w = w * v.w;
    } else {
        const float4 v0 = pb0[h];
        const float4 v1 = pb1[h];
        rb.x = w0b * v0.x + w1b * v1.x;
        rb.y = w0b * v0.y + w1b * v1.y;
        rb.z = w0b * v0.z + w1b * v1.z;
        rb.w = w0b * v0.w + w1b * v1.w;
    }

    float4* __restrict__ oa = (float4*)(out + (size_t)ta * kH);
    float4* __restrict__ ob = (float4*)(out + (size_t)tb * kH);
    oa[h] = ra;
    ob[h] = rb;
}

extern "C" void kernel_launch(void* const* d_in, const int* in_sizes, int n_in,
                              void* d_out, int out_size, void* d_ws, size_t ws_size,
                              hipStream_t stream) {
    // Input order per setup_inputs(): hidden_states (unused), expert_stack,
    // expert_weights, expert_indices.
    const float* expert_stack   = (const float*)d_in[1];
    const float* expert_weights = (const float*)d_in[2];
    const int*   expert_indices = (const int*)d_in[3];
    float* out = (float*)d_out;

    dim3 grid(kTokens / 2);   // 8192 blocks, 2 tokens each
    dim3 block(256);
    FusedExpertMixer_kernel<<<grid, block, 0, stream>>>(
        expert_stack, expert_weights, expert_indices, out);
}

// Round 3
// 33.346 us; speedup vs baseline: 1.0232x; 1.0232x over previous
//
#include <hip/hip_runtime.h>

// Problem constants (from reference): E=8, B=4, S=4096, H=1024, K=2
static constexpr int kB = 4;
static constexpr int kS = 4096;
static constexpr int kH = 1024;
static constexpr int kK = 2;
static constexpr int kTokens = kB * kS;                  // 16384
static constexpr size_t kBSH = (size_t)kB * kS * kH;     // 16,777,216

// One block per token; 256 threads x float4 = 1024 floats = one H-row.
// Measured 33.5 us (R1) = ~95% of the 6.29 TB/s float4-copy ceiling for the
// ~201 MB of unavoidable traffic. Dedup/multi-token variants were neutral (R2).
__global__ __launch_bounds__(256) void FusedExpertMixer_kernel(
    const float* __restrict__ expert_stack,   // [E,B,S,H]
    const float* __restrict__ expert_weights, // [B,S,K]
    const int*   __restrict__ expert_indices, // [B,S,K]
    float* __restrict__ out)                  // [B,S,H]
{
    const int t = blockIdx.x;                 // token index in [0, B*S)

    // Scalar (wave-uniform) loads of the two indices/weights for this token.
    const int   e0 = expert_indices[t * kK + 0];
    const int   e1 = expert_indices[t * kK + 1];
    const float w0 = expert_weights[t * kK + 0];
    const float w1 = expert_weights[t * kK + 1];

    const float4* __restrict__ a =
        (const float4*)(expert_stack + (size_t)e0 * kBSH + (size_t)t * kH);
    const float4* __restrict__ b =
        (const float4*)(expert_stack + (size_t)e1 * kBSH + (size_t)t * kH);
    float4* __restrict__ o = (float4*)(out + (size_t)t * kH);

    const int h = threadIdx.x;                // 0..255, one float4 each
    const float4 va = a[h];
    const float4 vb = b[h];
    float4 r;
    r.x = w0 * va.x + w1 * vb.x;
    r.y = w0 * va.y + w1 * vb.y;
    r.z = w0 * va.z + w1 * vb.z;
    r.w = w0 * va.w + w1 * vb.w;
    o[h] = r;
}

extern "C" void kernel_launch(void* const* d_in, const int* in_sizes, int n_in,
                              void* d_out, int out_size, void* d_ws, size_t ws_size,
                              hipStream_t stream) {
    // Input order per setup_inputs(): hidden_states (unused), expert_stack,
    // expert_weights, expert_indices.
    const float* expert_stack   = (const float*)d_in[1];
    const float* expert_weights = (const float*)d_in[2];
    const int*   expert_indices = (const int*)d_in[3];
    float* out = (float*)d_out;

    dim3 grid(kTokens);
    dim3 block(256);
    FusedExpertMixer_kernel<<<grid, block, 0, stream>>>(
        expert_stack, expert_weights, expert_indices, out);
}